// Round 7
// baseline (382.410 us; speedup 1.0000x reference)
//
#include <hip/hip_runtime.h>
#include <hip/hip_bf16.h>
#include <stdint.h>

// ---------------------------------------------------------------------------
// RG-LRU block: T=8192, D_MODEL=768, D_RNN=1024, KW=4.
// Round 7: dense GEMMs rebuilt as 2-stage pipelined, barrier-light kernels.
//  - BM=128, BN=64, BK=32, double-buffered LDS (24 KB), ~5 blocks/CU.
//  - Per iter: stage(next) -> s_waitcnt vmcnt(3) (wait only CURRENT buffer's
//    loads; next's stay in flight through compute) -> raw s_barrier ->
//    compute -> raw s_barrier.  No vmcnt(0) drain in steady state.
//  - conv_mfma (shift-reuse, r6), prep, scan kernels unchanged.
// ---------------------------------------------------------------------------

#define T_LEN 8192
#define DM 768
#define DR 1024
#define NC 128   // scan chunks
#define CL 64    // chunk length

typedef __bf16 bf16x8 __attribute__((ext_vector_type(8)));
typedef float  f32x4  __attribute__((ext_vector_type(4)));

#define AS1 __attribute__((address_space(1)))
#define AS3 __attribute__((address_space(3)))

// s_waitcnt immediates (gfx9): vm[3:0]|[15:14], exp[6:4], lgkm[11:8]
#define WAITCNT_VM3 0x0F73   // vmcnt(3)
#define WAITCNT_VM0 0x0F70   // vmcnt(0)

__device__ __forceinline__ void cp16_g2l(const void* g, void* l) {
    __builtin_amdgcn_global_load_lds((const AS1 void*)g, (AS3 void*)l, 16, 0, 0);
}

__device__ __forceinline__ float gelu_tanh(float x) {
    const float inner = 0.7978845608028654f * (x + 0.044715f * x * x * x);
    return 0.5f * x * (1.f + tanhf(inner));
}

// ---------------------------------------------------------------------------
// Pipelined dense GEMM: C[m,n] = sum_k A[m,k]*B[n,k] (+bias[n]).
// BM=128, BN=64, BK=32.  A: M x K bf16 (lda), B: N x K bf16.  K % 32 == 0.
// 32-wide LDS rows = 4 16B chunks; slot s at row r holds chunk s ^ ((r>>1)&3)
// (r4-proven 0-conflict pattern).
// EPI: 0 = fp32 +bias; 1 = bf16 +bias; 2 = split (gelu->Cv / +3-shift->D2).
// ---------------------------------------------------------------------------
template<int EPI>
__global__ __launch_bounds__(256, 5)
void gemm_mfma(const __hip_bfloat16* __restrict__ A,
               const __hip_bfloat16* __restrict__ B,
               const float* __restrict__ bias,
               void* __restrict__ Cv,
               int K, int lda, int N,
               __hip_bfloat16* __restrict__ D2)
{
    __shared__ __bf16 As[2][128 * 32];
    __shared__ __bf16 Bs[2][64 * 32];

    const int tid  = threadIdx.x;
    const int lane = tid & 63;
    const int wave = tid >> 6;
    const size_t m0 = (size_t)blockIdx.x * 128;   // XCD = blockIdx.x % 8
    const int    n0 = blockIdx.y * 64;
    const int wm = (wave >> 1) * 64;
    const int wn = (wave & 1) * 32;

    f32x4 acc[4][2];
#pragma unroll
    for (int i = 0; i < 4; ++i)
#pragma unroll
        for (int j = 0; j < 2; ++j)
            acc[i][j] = f32x4{0.f, 0.f, 0.f, 0.f};

    const int frow = lane & 15;
    const int fq   = lane >> 4;

    // staging: 3 cp16 per thread per k-tile (2 A + 1 B)
    const int arr0 = tid >> 2;            // A rows for q=0 (0..63) / q=1 (+64)
    const int agc  = (tid & 3);           // chunk slot
    auto stage = [&](int k0, int s) {
#pragma unroll
        for (int q = 0; q < 2; ++q) {
            const int rr = q * 64 + arr0;
            const int gc = agc ^ ((rr >> 1) & 3);
            cp16_g2l(A + (m0 + rr) * (size_t)lda + k0 + gc * 8,
                     &As[s][(q * 256 + tid) * 8]);
        }
        {
            const int rr = arr0;          // 0..63
            const int gc = agc ^ ((rr >> 1) & 3);
            cp16_g2l(B + (size_t)(n0 + rr) * K + k0 + gc * 8,
                     &Bs[s][tid * 8]);
        }
    };

    auto compute = [&](int s) {
        bf16x8 af[4], bfr[2];
#pragma unroll
        for (int mi = 0; mi < 4; ++mi) {
            const int R = wm + mi * 16 + frow;
            af[mi] = *(const bf16x8*)&As[s][R * 32 + ((fq ^ ((R >> 1) & 3)) * 8)];
        }
#pragma unroll
        for (int ni = 0; ni < 2; ++ni) {
            const int R = wn + ni * 16 + frow;
            bfr[ni] = *(const bf16x8*)&Bs[s][R * 32 + ((fq ^ ((R >> 1) & 3)) * 8)];
        }
#pragma unroll
        for (int mi = 0; mi < 4; ++mi)
#pragma unroll
            for (int ni = 0; ni < 2; ++ni)
                acc[mi][ni] = __builtin_amdgcn_mfma_f32_16x16x32_bf16(
                    af[mi], bfr[ni], acc[mi][ni], 0, 0, 0);
    };

    // ---- 2-stage pipelined K-loop (raw barriers, no vmcnt(0) drain) ----
    const int nk = K >> 5;
    stage(0, 0);
    for (int i = 0; i < nk; ++i) {
        const int s = i & 1;
        if (i + 1 < nk) {
            stage((i + 1) << 5, s ^ 1);
            __builtin_amdgcn_s_waitcnt(WAITCNT_VM3);  // current buf's 3 done
        } else {
            __builtin_amdgcn_s_waitcnt(WAITCNT_VM0);
        }
        __builtin_amdgcn_s_barrier();   // all waves: buf s full
        compute(s);
        __builtin_amdgcn_s_barrier();   // release: buf s may be overwritten
    }

    // C/D layout: col = lane&15, row = (lane>>4)*4 + reg
    const int er = fq * 4;
    const int ec = frow;
#pragma unroll
    for (int ni = 0; ni < 2; ++ni) {
        const int n = n0 + wn + ni * 16 + ec;
        const float bv = bias ? bias[n] : 0.f;
#pragma unroll
        for (int mi = 0; mi < 4; ++mi) {
#pragma unroll
            for (int r2 = 0; r2 < 4; ++r2) {
                const size_t m = m0 + wm + mi * 16 + er + r2;
                const float v = acc[mi][ni][r2] + bv;
                if (EPI == 0) {
                    ((float*)Cv)[m * (size_t)N + n] = v;
                } else if (EPI == 1) {
                    ((__hip_bfloat16*)Cv)[m * (size_t)N + n] = __float2bfloat16(v);
                } else {
                    if (n < 1024)
                        ((__hip_bfloat16*)Cv)[m * 1024 + n] = __float2bfloat16(gelu_tanh(v));
                    else
                        D2[(m + 3) * 1024 + (n - 1024)] = __float2bfloat16(v);
                }
            }
        }
    }
}

// ---------------------------------------------------------------------------
// Conv GEMM with shift reuse (unchanged from r6).
// ---------------------------------------------------------------------------
__global__ __launch_bounds__(256)
void conv_mfma(const __hip_bfloat16* __restrict__ bbp,
               const __hip_bfloat16* __restrict__ W,
               __hip_bfloat16* __restrict__ C)
{
    __shared__ __bf16 As[132 * 32];        // 8.25 KB halo tile
    __shared__ __bf16 Bs[4 * 128 * 32];    // 32 KB, 4 shift tiles

    const int tid  = threadIdx.x;
    const int lane = tid & 63;
    const int wave = tid >> 6;
    const size_t m0 = (size_t)blockIdx.x * 128;
    const int    n0 = blockIdx.y * 128;
    const int wm = (wave >> 1) * 64;
    const int wn = (wave & 1) * 64;

    f32x4 acc[4][4];
#pragma unroll
    for (int i = 0; i < 4; ++i)
#pragma unroll
        for (int j = 0; j < 4; ++j)
            acc[i][j] = f32x4{0.f, 0.f, 0.f, 0.f};

    const int frow = lane & 15;
    const int fq   = lane >> 4;

    for (int kc = 0; kc < 1024; kc += 32) {
        __syncthreads();
#pragma unroll
        for (int q = 0; q < 2; ++q) {
            const int lin = q * 256 + tid;
            const int rr  = lin >> 2;
            const int gc  = (lin & 3) ^ ((rr >> 1) & 3);
            cp16_g2l(bbp + (m0 + rr) * 1024 + kc + gc * 8, &As[lin * 8]);
        }
        if (tid < 16) {
            const int lin = 512 + tid;
            const int rr  = lin >> 2;
            const int gc  = (lin & 3) ^ ((rr >> 1) & 3);
            cp16_g2l(bbp + (m0 + rr) * 1024 + kc + gc * 8, &As[lin * 8]);
        }
#pragma unroll
        for (int s = 0; s < 4; ++s)
#pragma unroll
            for (int q = 0; q < 2; ++q) {
                const int lin = q * 256 + tid;
                const int rr  = lin >> 2;
                const int gc  = (lin & 3) ^ ((rr >> 1) & 3);
                cp16_g2l(W + (size_t)(n0 + rr) * 4096 + s * 1024 + kc + gc * 8,
                         &Bs[s * 4096 + lin * 8]);
            }
        __syncthreads();

#pragma unroll
        for (int s = 0; s < 4; ++s) {
            bf16x8 af[4], bfr[4];
#pragma unroll
            for (int mi = 0; mi < 4; ++mi) {
                const int R = wm + mi * 16 + frow + s;
                af[mi] = *(const bf16x8*)&As[R * 32 + ((fq ^ ((R >> 1) & 3)) * 8)];
            }
#pragma unroll
            for (int ni = 0; ni < 4; ++ni) {
                const int R = wn + ni * 16 + frow;
                bfr[ni] = *(const bf16x8*)&Bs[s * 4096 + R * 32 + ((fq ^ ((R >> 1) & 3)) * 8)];
            }
#pragma unroll
            for (int mi = 0; mi < 4; ++mi)
#pragma unroll
                for (int ni = 0; ni < 4; ++ni)
                    acc[mi][ni] = __builtin_amdgcn_mfma_f32_16x16x32_bf16(
                        af[mi], bfr[ni], acc[mi][ni], 0, 0, 0);
        }
    }

    const int er = fq * 4;
    const int ec = frow;
#pragma unroll
    for (int ni = 0; ni < 4; ++ni) {
        const int n = n0 + wn + ni * 16 + ec;
#pragma unroll
        for (int mi = 0; mi < 4; ++mi)
#pragma unroll
            for (int r2 = 0; r2 < 4; ++r2) {
                const size_t m = m0 + wm + mi * 16 + er + r2;
                C[m * 1024 + n] = __float2bfloat16(acc[mi][ni][r2]);
            }
    }
}

// One prep kernel: conversions + conv repack + bbp pad zero.
#define PREP_X   6291456            // 8192*768
#define PREP_W1  (PREP_X + 1572864) // + 2048*768
#define PREP_WRG (PREP_W1 + 2097152)// + 2048*1024
#define PREP_WO  (PREP_WRG + 786432)// + 768*1024
#define PREP_CW  (PREP_WO + 4194304)// + 1024*4096
#define PREP_TOT (PREP_CW + 3072)   // + pad rows
__global__ void prep_kernel(const float* __restrict__ x, const float* __restrict__ w1,
                            const float* __restrict__ w_rg, const float* __restrict__ w_out,
                            const float* __restrict__ conv_w,
                            __hip_bfloat16* __restrict__ xb, __hip_bfloat16* __restrict__ w1b,
                            __hip_bfloat16* __restrict__ w_rgb, __hip_bfloat16* __restrict__ w_outb,
                            __hip_bfloat16* __restrict__ wbigb, __hip_bfloat16* __restrict__ bbp)
{
    const int idx = blockIdx.x * 256 + threadIdx.x;
    if (idx < PREP_X) {
        xb[idx] = __float2bfloat16(x[idx]);
    } else if (idx < PREP_W1) {
        const int i = idx - PREP_X;  w1b[i] = __float2bfloat16(w1[i]);
    } else if (idx < PREP_WRG) {
        const int i = idx - PREP_W1; w_rgb[i] = __float2bfloat16(w_rg[i]);
    } else if (idx < PREP_WO) {
        const int i = idx - PREP_WRG; w_outb[i] = __float2bfloat16(w_out[i]);
    } else if (idx < PREP_CW) {
        const int n = idx - PREP_WO;
        const int o = n >> 12, r = n & 4095, k = r >> 10, i = r & 1023;
        wbigb[n] = __float2bfloat16(conv_w[o * 4096 + i * 4 + k]);
    } else {
        bbp[idx - PREP_CW] = __float2bfloat16(0.f);
    }
}

// Gates recomputed inline from g_pre (T x 2048 bf16) + bc (bf16):
__global__ void scan_pass1(const __hip_bfloat16* __restrict__ gp,
                           const __hip_bfloat16* __restrict__ bc,
                           const float* __restrict__ Lambda,
                           float* __restrict__ ch, float* __restrict__ ca)
{
    const int c = blockIdx.y * 256 + threadIdx.x;
    const int j = blockIdx.x;
    const float cl = -8.f * log1pf(expf(Lambda[c]));
    float h = 0.f, ap = 1.f;
    const int t0 = j * CL;
    for (int tt = 0; tt < CL; ++tt) {
        const int t = t0 + tt;
        const long gi = (long)t * 2048 + c;
        const float ig = 1.f / (1.f + expf(-__bfloat162float(gp[gi])));
        const float rg = 1.f / (1.f + expf(-__bfloat162float(gp[gi + 1024])));
        const float a  = expf(cl * rg);
        const float gx = sqrtf(fmaxf(0.f, 1.f - a * a)) * ig *
                         __bfloat162float(bc[(long)t * 1024 + c]);
        h  = fmaf(a, h, gx);
        ap *= a;
    }
    ch[j * 1024 + c] = h;
    ca[j * 1024 + c] = ap;
}

__global__ void scan_combine(float* __restrict__ ch, const float* __restrict__ ca)
{
    const int c = blockIdx.x * 256 + threadIdx.x;
    float carry = 0.f;
    for (int j = 0; j < NC; ++j) {
        const float hj = ch[j * 1024 + c];
        const float aj = ca[j * 1024 + c];
        ch[j * 1024 + c] = carry;
        carry = fmaf(aj, carry, hj);
    }
}

// Rescan with carry; z = ab * y -> bf16 (zb aliases bc: same-element RMW per thread).
__global__ void scan_pass2(const __hip_bfloat16* __restrict__ gp, const __hip_bfloat16* bc,
                           const float* __restrict__ Lambda,
                           const float* __restrict__ carry_in,
                           const __hip_bfloat16* __restrict__ ab,
                           __hip_bfloat16* zb)
{
    const int c = blockIdx.y * 256 + threadIdx.x;
    const int j = blockIdx.x;
    const float cl = -8.f * log1pf(expf(Lambda[c]));
    float h = carry_in[j * 1024 + c];
    const int t0 = j * CL;
    for (int tt = 0; tt < CL; ++tt) {
        const int t = t0 + tt;
        const long gi = (long)t * 2048 + c;
        const long bi = (long)t * 1024 + c;
        const float ig = 1.f / (1.f + expf(-__bfloat162float(gp[gi])));
        const float rg = 1.f / (1.f + expf(-__bfloat162float(gp[gi + 1024])));
        const float a  = expf(cl * rg);
        const float gx = sqrtf(fmaxf(0.f, 1.f - a * a)) * ig * __bfloat162float(bc[bi]);
        h = fmaf(a, h, gx);
        zb[bi] = __float2bfloat16(__bfloat162float(ab[bi]) * h);
    }
}

extern "C" void kernel_launch(void* const* d_in, const int* in_sizes, int n_in,
                              void* d_out, int out_size, void* d_ws, size_t ws_size,
                              hipStream_t stream)
{
    const float* x      = (const float*)d_in[0];
    const float* w1     = (const float*)d_in[1];
    const float* b1     = (const float*)d_in[2];
    const float* conv_w = (const float*)d_in[3];
    const float* w_rg   = (const float*)d_in[4];
    const float* b_rg   = (const float*)d_in[5];
    const float* w_out  = (const float*)d_in[6];
    const float* b_out  = (const float*)d_in[7];
    const float* Lambda = (const float*)d_in[8];
    float* out = (float*)d_out;
    (void)in_sizes; (void)n_in; (void)out_size; (void)ws_size;

    // ---- workspace layout (~110 MB) ----
    char* p = (char*)d_ws;
    auto alloc = [&](size_t bytes) { char* r = p; p += (bytes + 255) & ~255ULL; return r; };
    __hip_bfloat16* gpre  = (__hip_bfloat16*)alloc(8192ULL * 2048 * 2); // 32 MB
    __hip_bfloat16* ab    = (__hip_bfloat16*)alloc(8192ULL * 1024 * 2); // 16 MB
    __hip_bfloat16* bbp   = (__hip_bfloat16*)alloc(8200ULL * 1024 * 2); // 16.8 MB
    __hip_bfloat16* bcb   = (__hip_bfloat16*)alloc(8192ULL * 1024 * 2); // 16 MB (later zb)
    __hip_bfloat16* wbigb = (__hip_bfloat16*)alloc(1024ULL * 4096 * 2); // 8 MB
    __hip_bfloat16* xb    = (__hip_bfloat16*)alloc(8192ULL * 768 * 2);  // 12 MB
    __hip_bfloat16* w1b   = (__hip_bfloat16*)alloc(2048ULL * 768 * 2);  // 3 MB
    __hip_bfloat16* w_rgb = (__hip_bfloat16*)alloc(2048ULL * 1024 * 2); // 4 MB
    __hip_bfloat16* w_outb= (__hip_bfloat16*)alloc(768ULL * 1024 * 2);  // 1.5 MB
    float*          chv   = (float*)alloc(NC * 1024ULL * 4);
    float*          cav   = (float*)alloc(NC * 1024ULL * 4);
    __hip_bfloat16* zb    = bcb;   // overlay

    prep_kernel<<<PREP_TOT / 256, 256, 0, stream>>>(x, w1, w_rg, w_out, conv_w,
                                                    xb, w1b, w_rgb, w_outb, wbigb, bbp);

    // h = x @ w1.T + b1, fused split: ab = bf16(gelu), bbp = bf16 (rows +3)
    {
        dim3 grid(T_LEN / 128, 2048 / 64);
        gemm_mfma<2><<<grid, 256, 0, stream>>>(xb, w1b, b1, ab, DM, DM, 2048, bbp);
    }

    // bc = causal conv (shift-reuse kernel) -> bf16
    {
        dim3 grid(T_LEN / 128, 1024 / 128);
        conv_mfma<<<grid, 256, 0, stream>>>(bbp, wbigb, bcb);
    }

    // g_pre = bc @ w_rg.T + b_rg -> bf16
    {
        dim3 grid(T_LEN / 128, 2048 / 64);
        gemm_mfma<1><<<grid, 256, 0, stream>>>(bcb, w_rgb, b_rg, gpre, DR, DR, 2048, nullptr);
    }

    // chunked scan with fused gates; z = ab*y -> bf16 (overlays bcb)
    {
        dim3 gs(NC, DR / 256);
        scan_pass1<<<gs, 256, 0, stream>>>(gpre, bcb, Lambda, chv, cav);
        scan_combine<<<DR / 256, 256, 0, stream>>>(chv, cav);
        scan_pass2<<<gs, 256, 0, stream>>>(gpre, bcb, Lambda, chv, ab, zb);
    }

    // out = z @ w_out.T + b_out -> fp32
    {
        dim3 grid(T_LEN / 128, DM / 64);
        gemm_mfma<0><<<grid, 256, 0, stream>>>(zb, w_outb, b_out, out, DR, DR, DM, nullptr);
    }
}